// Round 4
// baseline (200.279 us; speedup 1.0000x reference)
//
#include <hip/hip_runtime.h>
#include <hip/hip_fp16.h>

#define ALPHA 0.2f
static constexpr int NN = 50000;
static constexpr long NE = (long)NN * 32;

typedef float f4v __attribute__((ext_vector_type(4)));
typedef float f2v __attribute__((ext_vector_type(2)));
typedef unsigned int u2v __attribute__((ext_vector_type(2)));

// workspace layout (float offsets)
static constexpr long WS_HN1 = 0;
static constexpr long WS_HN2 = NN;
static constexpr long WS_HE1 = 2L * NN;
static constexpr long WS_ST  = 3L * NN;             // 2*NN: [sum nn^2][sum ne^2]
static constexpr long WS_P   = 5L * NN;             // 512 floats of partials
static constexpr long WS_REC = 5L * NN + 512;       // uint2[NE] = 12.8 MB (8B aligned)
static constexpr long WS_HEV = WS_REC + 2L * NE;    // __half[NN*128] = 12.8 MB

// ---- kernel 1: h_v GEMM (50000x256 @ 256x64) + f16 pack + attention dots ----
__global__ __launch_bounds__(256) void k_hv(const float* __restrict__ A,
                                            const float* __restrict__ W,
                                            const float* __restrict__ a_node,
                                            const float* __restrict__ a_edge,
                                            __half* __restrict__ hev,
                                            float* __restrict__ hn1,
                                            float* __restrict__ hn2,
                                            float* __restrict__ he1) {
    __shared__ float As[16][65];
    __shared__ float Ws[16][64];
    const int t  = threadIdx.x;
    const int m0 = blockIdx.x * 64;
    const int tr = t >> 4, tc = t & 15;
    const int lr = t >> 2, seg = t & 3;
    const int wk = t >> 4, wc = t & 15;

    float acc[4][4] = {};
    for (int k0 = 0; k0 < 256; k0 += 16) {
        int row = m0 + lr;
        float4 av = make_float4(0.f, 0.f, 0.f, 0.f);
        if (row < NN)
            av = *reinterpret_cast<const float4*>(&A[(long)row * 256 + k0 + seg * 4]);
        As[seg*4+0][lr] = av.x; As[seg*4+1][lr] = av.y;
        As[seg*4+2][lr] = av.z; As[seg*4+3][lr] = av.w;
        *reinterpret_cast<float4*>(&Ws[wk][wc*4]) =
            *reinterpret_cast<const float4*>(&W[(k0 + wk) * 64 + wc * 4]);
        __syncthreads();
        #pragma unroll
        for (int kk = 0; kk < 16; ++kk) {
            float a0 = As[kk][tr*4+0], a1 = As[kk][tr*4+1];
            float a2 = As[kk][tr*4+2], a3 = As[kk][tr*4+3];
            float b0 = Ws[kk][tc*4+0], b1 = Ws[kk][tc*4+1];
            float b2 = Ws[kk][tc*4+2], b3 = Ws[kk][tc*4+3];
            acc[0][0] += a0*b0; acc[0][1] += a0*b1; acc[0][2] += a0*b2; acc[0][3] += a0*b3;
            acc[1][0] += a1*b0; acc[1][1] += a1*b1; acc[1][2] += a1*b2; acc[1][3] += a1*b3;
            acc[2][0] += a2*b0; acc[2][1] += a2*b1; acc[2][2] += a2*b2; acc[2][3] += a2*b3;
            acc[3][0] += a3*b0; acc[3][1] += a3*b1; acc[3][2] += a3*b2; acc[3][3] += a3*b3;
        }
        __syncthreads();
    }

    float an1[4], an2[4], ae1[4];
    #pragma unroll
    for (int j = 0; j < 4; ++j) {
        an1[j] = a_node[tc*4 + j];
        an2[j] = a_node[64 + tc*4 + j];
        ae1[j] = a_edge[tc*4 + j];
    }

    #pragma unroll
    for (int q = 0; q < 4; ++q) {
        float p1 = 0.f, p2 = 0.f, p3 = 0.f;
        #pragma unroll
        for (int j = 0; j < 4; ++j) {
            p1 += acc[q][j] * an1[j];
            p2 += acc[q][j] * an2[j];
            p3 += acc[q][j] * ae1[j];
        }
        #pragma unroll
        for (int m = 1; m <= 8; m <<= 1) {
            p1 += __shfl_xor(p1, m);
            p2 += __shfl_xor(p2, m);
            p3 += __shfl_xor(p3, m);
        }
        int row = m0 + tr * 4 + q;
        if (row < NN) {
            ushort4 hp;
            hp.x = __half_as_ushort(__float2half(acc[q][0]));
            hp.y = __half_as_ushort(__float2half(acc[q][1]));
            hp.z = __half_as_ushort(__float2half(acc[q][2]));
            hp.w = __half_as_ushort(__float2half(acc[q][3]));
            *reinterpret_cast<ushort4*>(&hev[(long)row * 128 + tc * 4]) = hp;
            if (tc == 0) { hn1[row] = p1; hn2[row] = p2; he1[row] = p3; }
        }
    }
}

// ---- kernel 2: e_v rows 0..49999 -> f16 second half of hev ----
__global__ __launch_bounds__(256) void k_ev(const float* __restrict__ ef,
                                            const float* __restrict__ We,
                                            __half* __restrict__ hev) {
    const int lane = threadIdx.x & 63, w = threadIdx.x >> 6;
    const int r = blockIdx.x * 4 + w;
    float acc = 0.f;
    #pragma unroll
    for (int k = 0; k < 32; ++k)
        acc += ef[(long)r * 32 + k] * We[k * 64 + lane];
    hev[(long)r * 128 + 64 + lane] = __float2half(acc);
}

// ---- kernel 3a: streaming attention -> compact records ----
__global__ __launch_bounds__(256) void k_att(const float* __restrict__ ef,
                                             const int*   __restrict__ edges,
                                             const float* __restrict__ a_edge,
                                             const float* __restrict__ hn1,
                                             const float* __restrict__ hn2,
                                             const float* __restrict__ he1,
                                             u2v* __restrict__ rec,
                                             float* __restrict__ st) {
    const int t = threadIdx.x;
    const int w = t >> 6, l = t & 63;
    const int n = blockIdx.x * 4 + w;
    const int i = l >> 1, h = l & 1;          // lane pair (2i,2i+1) owns edge i
    const long ebase = (long)n * 32;

    // edge-feature dot (nt: 205 MB single-use stream)
    const f4v* efb = reinterpret_cast<const f4v*>(&ef[(ebase + i) * 32 + h * 16]);
    float dot = 0.f;
    #pragma unroll
    for (int j = 0; j < 4; ++j) {
        f4v v = __builtin_nontemporal_load(efb + j);
        float4 a = *reinterpret_cast<const float4*>(&a_edge[64 + h * 16 + j * 4]);
        dot += v.x*a.x + v.y*a.y + v.z*a.z + v.w*a.w;
    }
    dot += __shfl_xor(dot, 1);

    const int d = __builtin_nontemporal_load(&edges[(ebase + i) * 2 + 1]);

    float attn = hn1[n] + hn2[d];
    attn = attn >= 0.f ? attn : ALPHA * attn;
    float wn = __expf(fminf(fmaxf(attn, -2.f), 2.f));

    float atte = he1[n] + dot;
    atte = atte >= 0.f ? atte : ALPHA * atte;
    float we = __expf(fminf(fmaxf(atte, -2.f), 2.f));

    // segment softmax: parity reduce sums each edge exactly once
    float dn = wn, de = we;
    #pragma unroll
    for (int m = 2; m <= 32; m <<= 1) { dn += __shfl_xor(dn, m); de += __shfl_xor(de, m); }
    float nn = wn / dn, ne = we / de;

    // variance partials (sum of weights == 1 analytically)
    float sqn = nn * nn, sqe = ne * ne;
    #pragma unroll
    for (int m = 2; m <= 32; m <<= 1) { sqn += __shfl_xor(sqn, m); sqe += __shfl_xor(sqe, m); }
    if (l == 0) { st[n] = sqn; st[NN + n] = sqe; }

    // record: {dst, half2(nn, ne)} written by even lanes
    if (h == 0) {
        __half2 p = __floats2half2_rn(nn, ne);
        u2v r;
        r.x = (unsigned int)d;
        r.y = *reinterpret_cast<unsigned int*>(&p);
        __builtin_nontemporal_store(r, &rec[ebase + i]);
    }
}

// ---- kernel 3b: pure gather-accumulate (no competing stream in L2/L3) ----
__global__ __launch_bounds__(256) void k_gather(const u2v* __restrict__ rec,
                                                const __half* __restrict__ hev,
                                                float* __restrict__ out) {
    const int t = threadIdx.x;
    const int w = t >> 6, l = t & 63;
    const int n = blockIdx.x * 4 + w;

    // lanes 0..31 hold the 32 records of node n
    u2v r = __builtin_nontemporal_load(&rec[(long)n * 32 + (l & 31)]);

    const bool isE = l >= 32;
    float a0 = 0.f, a1 = 0.f;
    #pragma unroll
    for (int b = 0; b < 4; ++b) {
        int dv[8]; unsigned int wv[8]; __half2 h2[8];
        #pragma unroll
        for (int u = 0; u < 8; ++u) {
            const int ii = b * 8 + u;
            dv[u] = __builtin_amdgcn_readlane((int)r.x, ii);
            wv[u] = (unsigned int)__builtin_amdgcn_readlane((int)r.y, ii);
            h2[u] = *reinterpret_cast<const __half2*>(&hev[(long)dv[u] * 128 + l * 2]);
        }
        #pragma unroll
        for (int u = 0; u < 8; ++u) {
            __half2 wp = *reinterpret_cast<__half2*>(&wv[u]);
            float wt = isE ? __high2float(wp) : __low2float(wp);
            float2 f = __half22float2(h2[u]);
            a0 = fmaf(wt, f.x, a0);
            a1 = fmaf(wt, f.y, a1);
        }
    }
    long off = isE ? ((long)NN * 64 + (long)n * 64 + (l - 32) * 2)
                   : ((long)n * 64 + l * 2);
    f2v o; o.x = a0; o.y = a1;
    __builtin_nontemporal_store(o, reinterpret_cast<f2v*>(&out[off]));
}

// ---- kernel 4a: stats reduction stage 1 ----
__global__ __launch_bounds__(256) void k_red1(const float* __restrict__ st,
                                              float* __restrict__ part) {
    const int t = threadIdx.x;
    const int n = blockIdx.x * 256 + t;
    float v0 = 0.f, v1 = 0.f;
    if (n < NN) { v0 = st[n]; v1 = st[NN + n]; }
    #pragma unroll
    for (int m = 1; m <= 32; m <<= 1) { v0 += __shfl_xor(v0, m); v1 += __shfl_xor(v1, m); }
    __shared__ float ls[4][2];
    const int wv = t >> 6;
    if ((t & 63) == 0) { ls[wv][0] = v0; ls[wv][1] = v1; }
    __syncthreads();
    if (t == 0) {
        part[(long)blockIdx.x * 2]     = ls[0][0] + ls[1][0] + ls[2][0] + ls[3][0];
        part[(long)blockIdx.x * 2 + 1] = ls[0][1] + ls[1][1] + ls[2][1] + ls[3][1];
    }
}

// ---- kernel 4b: final variances ----
__global__ __launch_bounds__(64) void k_red2(const float* __restrict__ part,
                                             float* __restrict__ out) {
    const int t = threadIdx.x;
    double v0 = 0.0, v1 = 0.0;
    for (int b = t; b < 196; b += 64) {
        v0 += (double)part[b * 2];
        v1 += (double)part[b * 2 + 1];
    }
    #pragma unroll
    for (int m = 1; m <= 32; m <<= 1) { v0 += __shfl_xor(v0, m); v1 += __shfl_xor(v1, m); }
    if (t == 0) {
        const double M = (double)NE;
        const double corr = (double)NN * (double)NN / M;   // (sum w)^2/M, sum w == NN
        out[6400000] = (float)((v0 - corr) / (M - 1.0));
        out[6400001] = (float)((v1 - corr) / (M - 1.0));
    }
}

extern "C" void kernel_launch(void* const* d_in, const int* in_sizes, int n_in,
                              void* d_out, int out_size, void* d_ws, size_t ws_size,
                              hipStream_t stream) {
    const float* node_fts = (const float*)d_in[0];
    const float* edge_fts = (const float*)d_in[1];
    const int*   edges    = (const int*)  d_in[2];
    const float* W_node   = (const float*)d_in[3];
    const float* W_edge   = (const float*)d_in[4];
    const float* a_node   = (const float*)d_in[5];
    const float* a_edge   = (const float*)d_in[6];
    float* out = (float*)d_out;
    float* ws  = (float*)d_ws;

    float*  hn1 = ws + WS_HN1;
    float*  hn2 = ws + WS_HN2;
    float*  he1 = ws + WS_HE1;
    float*  st  = ws + WS_ST;
    float*  prt = ws + WS_P;
    u2v*    rec = (u2v*)(ws + WS_REC);
    __half* hev = (__half*)(ws + WS_HEV);

    k_ev    <<<NN / 4, 256, 0, stream>>>(edge_fts, W_edge, hev);
    k_hv    <<<(NN + 63) / 64, 256, 0, stream>>>(node_fts, W_node, a_node, a_edge,
                                                 hev, hn1, hn2, he1);
    k_att   <<<NN / 4, 256, 0, stream>>>(edge_fts, edges, a_edge, hn1, hn2, he1,
                                         rec, st);
    k_gather<<<NN / 4, 256, 0, stream>>>(rec, hev, out);
    k_red1  <<<196, 256, 0, stream>>>(st, prt);
    k_red2  <<<1, 64, 0, stream>>>(prt, out);
}

// Round 5
// 166.546 us; speedup vs baseline: 1.2025x; 1.2025x over previous
//
#include <hip/hip_runtime.h>
#include <hip/hip_fp16.h>

#define ALPHA 0.2f
static constexpr int NN = 50000;
static constexpr long NE = (long)NN * 32;

// workspace layout (float offsets)
static constexpr long WS_HN1 = 0;
static constexpr long WS_HN2 = NN;
static constexpr long WS_HE1 = 2L * NN;
static constexpr long WS_ST  = 3L * NN;        // 2*NN: [sum nn^2][sum ne^2]
static constexpr long WS_P   = 5L * NN;        // 512 floats of partials
static constexpr long WS_HEV = 5L * NN + 512;  // __half[NN*128], 16B-aligned

// ---- kernel 1: h_v GEMM (50000x256 @ 256x64) + f16 pack + attention dots ----
__global__ __launch_bounds__(256) void k_hv(const float* __restrict__ A,
                                            const float* __restrict__ W,
                                            const float* __restrict__ a_node,
                                            const float* __restrict__ a_edge,
                                            __half* __restrict__ hev,
                                            float* __restrict__ hn1,
                                            float* __restrict__ hn2,
                                            float* __restrict__ he1) {
    __shared__ float As[16][65];
    __shared__ float Ws[16][64];
    const int t  = threadIdx.x;
    const int m0 = blockIdx.x * 64;
    const int tr = t >> 4, tc = t & 15;
    const int lr = t >> 2, seg = t & 3;
    const int wk = t >> 4, wc = t & 15;

    float acc[4][4] = {};
    for (int k0 = 0; k0 < 256; k0 += 16) {
        int row = m0 + lr;
        float4 av = make_float4(0.f, 0.f, 0.f, 0.f);
        if (row < NN)
            av = *reinterpret_cast<const float4*>(&A[(long)row * 256 + k0 + seg * 4]);
        As[seg*4+0][lr] = av.x; As[seg*4+1][lr] = av.y;
        As[seg*4+2][lr] = av.z; As[seg*4+3][lr] = av.w;
        *reinterpret_cast<float4*>(&Ws[wk][wc*4]) =
            *reinterpret_cast<const float4*>(&W[(k0 + wk) * 64 + wc * 4]);
        __syncthreads();
        #pragma unroll
        for (int kk = 0; kk < 16; ++kk) {
            float a0 = As[kk][tr*4+0], a1 = As[kk][tr*4+1];
            float a2 = As[kk][tr*4+2], a3 = As[kk][tr*4+3];
            float b0 = Ws[kk][tc*4+0], b1 = Ws[kk][tc*4+1];
            float b2 = Ws[kk][tc*4+2], b3 = Ws[kk][tc*4+3];
            acc[0][0] += a0*b0; acc[0][1] += a0*b1; acc[0][2] += a0*b2; acc[0][3] += a0*b3;
            acc[1][0] += a1*b0; acc[1][1] += a1*b1; acc[1][2] += a1*b2; acc[1][3] += a1*b3;
            acc[2][0] += a2*b0; acc[2][1] += a2*b1; acc[2][2] += a2*b2; acc[2][3] += a2*b3;
            acc[3][0] += a3*b0; acc[3][1] += a3*b1; acc[3][2] += a3*b2; acc[3][3] += a3*b3;
        }
        __syncthreads();
    }

    float an1[4], an2[4], ae1[4];
    #pragma unroll
    for (int j = 0; j < 4; ++j) {
        an1[j] = a_node[tc*4 + j];
        an2[j] = a_node[64 + tc*4 + j];
        ae1[j] = a_edge[tc*4 + j];
    }

    #pragma unroll
    for (int q = 0; q < 4; ++q) {
        float p1 = 0.f, p2 = 0.f, p3 = 0.f;
        #pragma unroll
        for (int j = 0; j < 4; ++j) {
            p1 += acc[q][j] * an1[j];
            p2 += acc[q][j] * an2[j];
            p3 += acc[q][j] * ae1[j];
        }
        #pragma unroll
        for (int m = 1; m <= 8; m <<= 1) {
            p1 += __shfl_xor(p1, m);
            p2 += __shfl_xor(p2, m);
            p3 += __shfl_xor(p3, m);
        }
        int row = m0 + tr * 4 + q;
        if (row < NN) {
            ushort4 hp;
            hp.x = __half_as_ushort(__float2half(acc[q][0]));
            hp.y = __half_as_ushort(__float2half(acc[q][1]));
            hp.z = __half_as_ushort(__float2half(acc[q][2]));
            hp.w = __half_as_ushort(__float2half(acc[q][3]));
            *reinterpret_cast<ushort4*>(&hev[(long)row * 128 + tc * 4]) = hp;
            if (tc == 0) { hn1[row] = p1; hn2[row] = p2; he1[row] = p3; }
        }
    }
}

// ---- kernel 2: e_v rows 0..49999 -> f16 second half of hev ----
__global__ __launch_bounds__(256) void k_ev(const float* __restrict__ ef,
                                            const float* __restrict__ We,
                                            __half* __restrict__ hev) {
    const int lane = threadIdx.x & 63, w = threadIdx.x >> 6;
    const int r = blockIdx.x * 4 + w;
    float acc = 0.f;
    #pragma unroll
    for (int k = 0; k < 32; ++k)
        acc += ef[(long)r * 32 + k] * We[k * 64 + lane];
    hev[(long)r * 128 + 64 + lane] = __float2half(acc);
}

// ---- kernel 3: attention + gather, with explicit load scheduling ----
// Order: dst load -> 16B x4 ef stream loads -> ALL 32 gather loads issued
// (32 outstanding VMEM) -> dot+softmax compute overlaps gather latency ->
// FMA drain uses in-order vmcnt partial waits.
__global__ __launch_bounds__(256) void k_edge(const float* __restrict__ ef,
                                              const int*   __restrict__ edges,
                                              const float* __restrict__ a_edge,
                                              const float* __restrict__ hn1,
                                              const float* __restrict__ hn2,
                                              const float* __restrict__ he1,
                                              const __half* __restrict__ hev,
                                              float* __restrict__ st,
                                              float* __restrict__ out) {
    const int t = threadIdx.x;
    const int w = t >> 6, l = t & 63;
    const int n = blockIdx.x * 4 + w;
    const int i = l >> 1, h = l & 1;          // lane pair (2i,2i+1) owns edge i
    const long ebase = (long)n * 32;

    // (1) dst index first — gather addresses depend on it
    const int d = edges[(ebase + i) * 2 + 1];

    // (2) streaming ef loads (HBM) in flight while we wait for d
    const float4* efb = reinterpret_cast<const float4*>(&ef[(ebase + i) * 32 + h * 16]);
    float4 v0 = efb[0], v1 = efb[1], v2 = efb[2], v3 = efb[3];

    // (3) issue ALL 32 gather loads: SGPR row base via readlane + lane offset
    __half2 h2[32];
    #pragma unroll
    for (int u = 0; u < 32; ++u) {
        int du = __builtin_amdgcn_readlane(d, 2 * u);
        h2[u] = *reinterpret_cast<const __half2*>(&hev[(long)du * 128 + l * 2]);
    }

    // (4) compute overlaps outstanding gathers
    float dot;
    {
        const float* ae = &a_edge[64 + h * 16];
        float4 a0q = *reinterpret_cast<const float4*>(ae);
        float4 a1q = *reinterpret_cast<const float4*>(ae + 4);
        float4 a2q = *reinterpret_cast<const float4*>(ae + 8);
        float4 a3q = *reinterpret_cast<const float4*>(ae + 12);
        dot = v0.x*a0q.x + v0.y*a0q.y + v0.z*a0q.z + v0.w*a0q.w
            + v1.x*a1q.x + v1.y*a1q.y + v1.z*a1q.z + v1.w*a1q.w
            + v2.x*a2q.x + v2.y*a2q.y + v2.z*a2q.z + v2.w*a2q.w
            + v3.x*a3q.x + v3.y*a3q.y + v3.z*a3q.z + v3.w*a3q.w;
    }
    dot += __shfl_xor(dot, 1);

    float attn = hn1[n] + hn2[d];
    attn = attn >= 0.f ? attn : ALPHA * attn;
    float wn = __expf(fminf(fmaxf(attn, -2.f), 2.f));

    float atte = he1[n] + dot;
    atte = atte >= 0.f ? atte : ALPHA * atte;
    float we = __expf(fminf(fmaxf(atte, -2.f), 2.f));

    // segment softmax: parity reduce sums each edge exactly once
    float dn = wn, de = we;
    #pragma unroll
    for (int m = 2; m <= 32; m <<= 1) { dn += __shfl_xor(dn, m); de += __shfl_xor(de, m); }
    float nn = wn / dn, ne = we / de;

    // variance partials (sum of weights == 1 analytically)
    float sqn = nn * nn, sqe = ne * ne;
    #pragma unroll
    for (int m = 2; m <= 32; m <<= 1) { sqn += __shfl_xor(sqn, m); sqe += __shfl_xor(sqe, m); }
    if (l == 0) { st[n] = sqn; st[NN + n] = sqe; }

    // pack (nn,ne) once per edge so the drain needs one readlane per edge
    __half2 wpk = __floats2half2_rn(nn, ne);
    unsigned int wbits = *reinterpret_cast<unsigned int*>(&wpk);

    // (5) FMA drain — h2[u] consumed in issue order (partial vmcnt waits)
    const bool isE = l >= 32;
    float a0 = 0.f, a1 = 0.f;
    #pragma unroll
    for (int u = 0; u < 32; ++u) {
        unsigned int wv = (unsigned int)__builtin_amdgcn_readlane((int)wbits, 2 * u);
        __half2 wp = *reinterpret_cast<__half2*>(&wv);
        float wt = isE ? __high2float(wp) : __low2float(wp);
        float2 f = __half22float2(h2[u]);
        a0 = fmaf(wt, f.x, a0);
        a1 = fmaf(wt, f.y, a1);
    }
    long off = isE ? ((long)NN * 64 + (long)n * 64 + (l - 32) * 2)
                   : ((long)n * 64 + l * 2);
    *reinterpret_cast<float2*>(&out[off]) = make_float2(a0, a1);
}

// ---- kernel 4a: stats reduction stage 1 ----
__global__ __launch_bounds__(256) void k_red1(const float* __restrict__ st,
                                              float* __restrict__ part) {
    const int t = threadIdx.x;
    const int n = blockIdx.x * 256 + t;
    float v0 = 0.f, v1 = 0.f;
    if (n < NN) { v0 = st[n]; v1 = st[NN + n]; }
    #pragma unroll
    for (int m = 1; m <= 32; m <<= 1) { v0 += __shfl_xor(v0, m); v1 += __shfl_xor(v1, m); }
    __shared__ float ls[4][2];
    const int wv = t >> 6;
    if ((t & 63) == 0) { ls[wv][0] = v0; ls[wv][1] = v1; }
    __syncthreads();
    if (t == 0) {
        part[(long)blockIdx.x * 2]     = ls[0][0] + ls[1][0] + ls[2][0] + ls[3][0];
        part[(long)blockIdx.x * 2 + 1] = ls[0][1] + ls[1][1] + ls[2][1] + ls[3][1];
    }
}

// ---- kernel 4b: final variances ----
__global__ __launch_bounds__(64) void k_red2(const float* __restrict__ part,
                                             float* __restrict__ out) {
    const int t = threadIdx.x;
    double v0 = 0.0, v1 = 0.0;
    for (int b = t; b < 196; b += 64) {
        v0 += (double)part[b * 2];
        v1 += (double)part[b * 2 + 1];
    }
    #pragma unroll
    for (int m = 1; m <= 32; m <<= 1) { v0 += __shfl_xor(v0, m); v1 += __shfl_xor(v1, m); }
    if (t == 0) {
        const double M = (double)NE;
        const double corr = (double)NN * (double)NN / M;   // (sum w)^2/M, sum w == NN
        out[6400000] = (float)((v0 - corr) / (M - 1.0));
        out[6400001] = (float)((v1 - corr) / (M - 1.0));
    }
}

extern "C" void kernel_launch(void* const* d_in, const int* in_sizes, int n_in,
                              void* d_out, int out_size, void* d_ws, size_t ws_size,
                              hipStream_t stream) {
    const float* node_fts = (const float*)d_in[0];
    const float* edge_fts = (const float*)d_in[1];
    const int*   edges    = (const int*)  d_in[2];
    const float* W_node   = (const float*)d_in[3];
    const float* W_edge   = (const float*)d_in[4];
    const float* a_node   = (const float*)d_in[5];
    const float* a_edge   = (const float*)d_in[6];
    float* out = (float*)d_out;
    float* ws  = (float*)d_ws;

    float*  hn1 = ws + WS_HN1;
    float*  hn2 = ws + WS_HN2;
    float*  he1 = ws + WS_HE1;
    float*  st  = ws + WS_ST;
    float*  prt = ws + WS_P;
    __half* hev = (__half*)(ws + WS_HEV);

    k_hv  <<<(NN + 63) / 64, 256, 0, stream>>>(node_fts, W_node, a_node, a_edge,
                                               hev, hn1, hn2, he1);
    k_ev  <<<NN / 4, 256, 0, stream>>>(edge_fts, W_edge, hev);
    k_edge<<<NN / 4, 256, 0, stream>>>(edge_fts, edges, a_edge, hn1, hn2, he1,
                                       hev, st, out);
    k_red1<<<196, 256, 0, stream>>>(st, prt);
    k_red2<<<1, 64, 0, stream>>>(prt, out);
}